// Round 11
// baseline (366.283 us; speedup 1.0000x reference)
//
#include <hip/hip_runtime.h>
#include <cstdint>
#include <cstddef>

// T=8192 tokens, E=64 experts, D=2048, capacity=2*ceil(T/E)=256
#define T_TOK 8192
#define NE    64
#define ND    2048
#define CAP   256

#define GB2 256    // gemm blocks: 128 token-tiles x 2 K-halves
#define NT  16     // k-tiles per gemm block (K/2 = 1024, tile 64)
#define MEB_B 128  // meb rows
#define ZB  2048   // zero blocks

// native clang vector type: __builtin_nontemporal_store requires it
typedef float f4v __attribute__((ext_vector_type(4)));

// ---------------------------------------------------------------- zero fill
// R11 (= R10 intent, fixed compile): NON-TEMPORAL stores. Theory: plain
// stores suffer L2 write-allocate (line fetched from HBM before overwrite)
// => ~2x traffic => observed ~3.8 TB/s in R9. nt (no-allocate) stores should
// reach ~6.3 TB/s like the runtime's fillBufferAligned (WRITE 4.3GB, FETCH~0).
__global__ __launch_bounds__(256) void k_zero(f4v* __restrict__ o4, long n4,
                                              float* __restrict__ o, long n) {
  long i = (long)blockIdx.x * 256 + threadIdx.x;
  const long stride = (long)ZB * 256;
  const f4v z = {0.f, 0.f, 0.f, 0.f};
  for (; i < n4; i += stride) __builtin_nontemporal_store(z, o4 + i);
  if (blockIdx.x == 0 && threadIdx.x == 0) {
    for (long j = n4 * 4; j < n; ++j) __builtin_nontemporal_store(0.f, o + j);
  }
}

// ---------------- kernel G: split-K gate GEMM -> lp partials ----------------
// 64tok x 64exp x K/2 fp32 GEMM per block; register-prefetch pipeline.
__global__ __launch_bounds__(256) void kG(
    const float* __restrict__ x, const float* __restrict__ wg,
    float* __restrict__ lp) {
  __shared__ float xs[64][68];   // x tile [token][k], row stride 68
  __shared__ float wk[64][68];   // wg tile TRANSPOSED [k][expert]

  const int tid = threadIdx.x;
  const int tb = blockIdx.x >> 1;   // token tile 0..127
  const int kb = blockIdx.x & 1;    // K half
  const int t0 = tb * 64;
  const int k0 = kb * (ND / 2);
  const int ty4 = (tid >> 4) << 2;  // token group base (4 tokens)
  const int tx4 = (tid & 15) << 2;  // expert group base (4 experts)

  int srow[4], scol[4];
#pragma unroll
  for (int i = 0; i < 4; ++i) {
    const int s = tid + i * 256;
    srow[i] = s >> 4;
    scol[i] = (s & 15) << 2;
  }

  float acc[4][4];
#pragma unroll
  for (int i = 0; i < 4; ++i)
#pragma unroll
    for (int j = 0; j < 4; ++j) acc[i][j] = 0.f;

  float4 rx[4], rw[4];
#pragma unroll
  for (int i = 0; i < 4; ++i) {
    rx[i] = *reinterpret_cast<const float4*>(x + (size_t)(t0 + srow[i]) * ND + k0 + scol[i]);
    rw[i] = *reinterpret_cast<const float4*>(wg + (size_t)srow[i] * ND + k0 + scol[i]);
  }

  for (int tt = 0; tt < NT; ++tt) {
    __syncthreads();
#pragma unroll
    for (int i = 0; i < 4; ++i) {
      *reinterpret_cast<float4*>(&xs[srow[i]][scol[i]]) = rx[i];
      wk[scol[i] + 0][srow[i]] = rw[i].x;
      wk[scol[i] + 1][srow[i]] = rw[i].y;
      wk[scol[i] + 2][srow[i]] = rw[i].z;
      wk[scol[i] + 3][srow[i]] = rw[i].w;
    }
    __syncthreads();
    if (tt + 1 < NT) {
      const int kt = k0 + (tt + 1) * 64;
#pragma unroll
      for (int i = 0; i < 4; ++i) {
        rx[i] = *reinterpret_cast<const float4*>(x + (size_t)(t0 + srow[i]) * ND + kt + scol[i]);
        rw[i] = *reinterpret_cast<const float4*>(wg + (size_t)srow[i] * ND + kt + scol[i]);
      }
    }
#pragma unroll 2
    for (int k4 = 0; k4 < 64; k4 += 4) {
      float4 xa[4];
#pragma unroll
      for (int i = 0; i < 4; ++i)
        xa[i] = *reinterpret_cast<const float4*>(&xs[ty4 + i][k4]);
#define KKSTEP(F, O)                                                        \
      {                                                                     \
        float4 wb = *reinterpret_cast<const float4*>(&wk[k4 + O][tx4]);     \
        _Pragma("unroll")                                                   \
        for (int i = 0; i < 4; ++i) {                                       \
          const float a = xa[i].F;                                          \
          acc[i][0] = fmaf(a, wb.x, acc[i][0]);                             \
          acc[i][1] = fmaf(a, wb.y, acc[i][1]);                             \
          acc[i][2] = fmaf(a, wb.z, acc[i][2]);                             \
          acc[i][3] = fmaf(a, wb.w, acc[i][3]);                             \
        }                                                                   \
      }
      KKSTEP(x, 0) KKSTEP(y, 1) KKSTEP(z, 2) KKSTEP(w, 3)
#undef KKSTEP
    }
  }

  float* dst = lp + (size_t)kb * T_TOK * NE;
#pragma unroll
  for (int i = 0; i < 4; ++i) {
    float4 v = make_float4(acc[i][0], acc[i][1], acc[i][2], acc[i][3]);
    *reinterpret_cast<float4*>(dst + (size_t)(t0 + ty4 + i) * NE + tx4) = v;
  }
}

// ------------------------------------------------- epilogue: softmax/argmax
__global__ __launch_bounds__(256) void k_epi(
    const float* __restrict__ lp, const float* __restrict__ gum,
    int* __restrict__ idx1o, int* __restrict__ idx2o,
    float* __restrict__ g1o, float* __restrict__ g2o,
    float* __restrict__ meb) {
  __shared__ float mred[4][NE];
  const int tid = threadIdx.x;
  const int wave = tid >> 6;
  const int lane = tid & 63;
  const int t0 = blockIdx.x * 64;
  float meacc = 0.f;
  for (int tt = wave * 16; tt < wave * 16 + 16; ++tt) {
    const int t = t0 + tt;
    const float logit = lp[(size_t)t * NE + lane] +
                        lp[(size_t)(T_TOK + t) * NE + lane];
    float m = logit;
#pragma unroll
    for (int o = 32; o; o >>= 1) m = fmaxf(m, __shfl_xor(m, o));
    const float ex = expf(logit - m);
    float s = ex;
#pragma unroll
    for (int o = 32; o; o >>= 1) s += __shfl_xor(s, o);
    const float gate = ex / s;
    meacc += gate;
    float v1 = logit; int i1 = lane;
#pragma unroll
    for (int o = 32; o; o >>= 1) {
      float vv = __shfl_xor(v1, o); int jj = __shfl_xor(i1, o);
      if (vv > v1 || (vv == v1 && jj < i1)) { v1 = vv; i1 = jj; }
    }
    float v2 = (lane == i1) ? -__builtin_inff() : logit + gum[(size_t)t * NE + lane];
    int i2 = lane;
#pragma unroll
    for (int o = 32; o; o >>= 1) {
      float vv = __shfl_xor(v2, o); int jj = __shfl_xor(i2, o);
      if (vv > v2 || (vv == v2 && jj < i2)) { v2 = vv; i2 = jj; }
    }
    const float gv1 = __shfl(gate, i1);
    const float gv2 = __shfl(gate, i2);
    if (lane == 0) {
      idx1o[t] = i1; idx2o[t] = i2; g1o[t] = gv1; g2o[t] = gv2;
    }
  }
  mred[wave][lane] = meacc;
  __syncthreads();
  if (wave == 0) {
    float sm = mred[0][lane] + mred[1][lane] + mred[2][lane] + mred[3][lane];
    meb[(size_t)blockIdx.x * NE + lane] = sm;
  }
}

// ------------------------------------------------- per-expert token scan
__global__ __launch_bounds__(256) void k_scan(
    const int* __restrict__ idx1, const int* __restrict__ idx2,
    int* __restrict__ loc1, int* __restrict__ loc2, int* __restrict__ cnt1) {
  const int e = blockIdx.x;
  const int tid = threadIdx.x;
  const int base = tid * 32;
  int c1 = 0, c2 = 0;
  for (int i = 0; i < 32; ++i) {
    c1 += (idx1[base + i] == e);
    c2 += (idx2[base + i] == e);
  }
  const int lane = tid & 63, wave = tid >> 6;
  int s1 = c1, s2 = c2;
#pragma unroll
  for (int o = 1; o < 64; o <<= 1) {
    int t1 = __shfl_up(s1, o), t2 = __shfl_up(s2, o);
    if (lane >= o) { s1 += t1; s2 += t2; }
  }
  __shared__ int wt1[4], wt2[4];
  if (lane == 63) { wt1[wave] = s1; wt2[wave] = s2; }
  __syncthreads();
  int off1 = 0, off2 = 0, tot1 = 0;
#pragma unroll
  for (int w = 0; w < 4; ++w) {
    tot1 += wt1[w];
    if (w < wave) { off1 += wt1[w]; off2 += wt2[w]; }
  }
  int p1 = off1 + s1 - c1;
  int p2 = off2 + s2 - c2 + tot1;
  for (int i = 0; i < 32; ++i) {
    if (idx1[base + i] == e) loc1[base + i] = p1++;
    if (idx2[base + i] == e) loc2[base + i] = p2++;
  }
  if (tid == 0) cnt1[e] = tot1;
}

// ------------------------------------- scatter combine/dispatch + l_aux
__global__ __launch_bounds__(256) void k_scat(
    const int* __restrict__ idx1, const int* __restrict__ idx2,
    const float* __restrict__ g1, const float* __restrict__ g2,
    const int* __restrict__ loc1, const int* __restrict__ loc2,
    const float* __restrict__ meb, const int* __restrict__ cnt1,
    float* __restrict__ out) {
  if (blockIdx.x == T_TOK / 256) {
    const int lane = threadIdx.x;
    if (lane >= 64) return;
    float ms = 0.f;
    for (int b = 0; b < MEB_B; ++b) ms += meb[(size_t)b * NE + lane];
    const float me = ms / (float)T_TOK;
    const float ce = (float)cnt1[lane] / (float)T_TOK;
    float v = me * ce;
#pragma unroll
    for (int o = 32; o; o >>= 1) v += __shfl_xor(v, o);
    if (lane == 0) out[0] = v * (float)NE;
    return;
  }
  const int t = blockIdx.x * 256 + threadIdx.x;
  const int l1 = loc1[t], l2 = loc2[t];
  const bool k1 = l1 < CAP, k2 = l2 < CAP;
  const float a = k1 ? g1[t] : 0.f;
  const float b = k2 ? g2[t] : 0.f;
  const float denom = fmaxf(a + b, 1.1920929e-07f);
  float* cw = out + 1;
  float* dm = out + 1 + (size_t)T_TOK * NE * CAP;
  if (k1) {
    size_t o = ((size_t)t * NE + idx1[t]) * CAP + l1;
    cw[o] = a / denom; dm[o] = 1.0f;
  }
  if (k2) {
    size_t o = ((size_t)t * NE + idx2[t]) * CAP + l2;
    cw[o] = b / denom; dm[o] = 1.0f;
  }
}

// ---------------------------------------------------------------- launcher
extern "C" void kernel_launch(void* const* d_in, const int* in_sizes, int n_in,
                              void* d_out, int out_size, void* d_ws, size_t ws_size,
                              hipStream_t stream) {
  const float* x   = (const float*)d_in[0];   // [8192, 2048]
  const float* wg  = (const float*)d_in[1];   // [64, 2048]
  const float* gum = (const float*)d_in[2];   // [8192, 64]
  float* out = (float*)d_out;

  // workspace layout (~4.5 MB)
  char* ws = (char*)d_ws;
  float* lp   = (float*)(ws + 0);             // [2][8192][64] = 4 MB
  int*   idx1 = (int*)(ws + 4194304);
  int*   idx2 = (int*)(ws + 4227072);
  float* g1   = (float*)(ws + 4259840);
  float* g2   = (float*)(ws + 4292608);
  int*   loc1 = (int*)(ws + 4325376);
  int*   loc2 = (int*)(ws + 4358144);
  int*   cnt1 = (int*)(ws + 4390912);
  float* meb  = (float*)(ws + 4391168);       // [128][64]

  const long n  = (long)out_size;             // 268,435,457 floats
  const long n4 = n >> 2;

  // serial chain; ONLY change vs R9: nt stores in k_zero
  k_zero<<<dim3(ZB), dim3(256), 0, stream>>>((f4v*)out, n4, out, n);
  kG<<<dim3(GB2), dim3(256), 0, stream>>>(x, wg, lp);
  k_epi<<<dim3(T_TOK / 64), dim3(256), 0, stream>>>(lp, gum, idx1, idx2, g1, g2, meb);
  k_scan<<<dim3(NE), dim3(256), 0, stream>>>(idx1, idx2, loc1, loc2, cnt1);
  k_scat<<<dim3(T_TOK / 256 + 1), dim3(256), 0, stream>>>(
      idx1, idx2, g1, g2, loc1, loc2, meb, cnt1, out);
}

// Round 12
// 294.763 us; speedup vs baseline: 1.2426x; 1.2426x over previous
//
#include <hip/hip_runtime.h>
#include <cstdint>
#include <cstddef>

// T=8192 tokens, E=64 experts, D=2048, capacity=2*ceil(T/E)=256
#define T_TOK 8192
#define NE    64
#define ND    2048
#define CAP   256

#define GB2 256    // gemm blocks: 128 token-tiles x 2 K-halves
#define NT  16     // k-tiles per gemm block (K/2 = 1024, tile 64)
#define MEB_B 128  // meb rows
#define ZB  256    // zero blocks  (R12: 2048 -> 256, ~4 waves/CU like rocclr fill)

// ---------------------------------------------------------------- zero fill
// R12 theory: fillBufferAligned hits 6.5 TB/s at ~10.8% occupancy (~3.4
// waves/CU) => write BW peaks with FEW waves streaming long sequential
// store runs; 2048-block versions (8+ waves/CU) thrash write queues
// (3.8 TB/s, R9; nt even worse, R11). Single change vs R9: ZB 2048 -> 256.
__global__ __launch_bounds__(256) void k_zero(float4* __restrict__ o4, long n4,
                                              float* __restrict__ o, long n) {
  long i = (long)blockIdx.x * 256 + threadIdx.x;
  const long stride = (long)ZB * 256;
  const float4 z = make_float4(0.f, 0.f, 0.f, 0.f);
  for (; i < n4; i += stride) o4[i] = z;
  if (blockIdx.x == 0 && threadIdx.x == 0) {
    for (long j = n4 * 4; j < n; ++j) o[j] = 0.f;  // odd tail element
  }
}

// ---------------- kernel G: split-K gate GEMM -> lp partials ----------------
// 64tok x 64exp x K/2 fp32 GEMM per block; register-prefetch pipeline.
__global__ __launch_bounds__(256) void kG(
    const float* __restrict__ x, const float* __restrict__ wg,
    float* __restrict__ lp) {
  __shared__ float xs[64][68];   // x tile [token][k], row stride 68
  __shared__ float wk[64][68];   // wg tile TRANSPOSED [k][expert]

  const int tid = threadIdx.x;
  const int tb = blockIdx.x >> 1;   // token tile 0..127
  const int kb = blockIdx.x & 1;    // K half
  const int t0 = tb * 64;
  const int k0 = kb * (ND / 2);
  const int ty4 = (tid >> 4) << 2;  // token group base (4 tokens)
  const int tx4 = (tid & 15) << 2;  // expert group base (4 experts)

  int srow[4], scol[4];
#pragma unroll
  for (int i = 0; i < 4; ++i) {
    const int s = tid + i * 256;
    srow[i] = s >> 4;
    scol[i] = (s & 15) << 2;
  }

  float acc[4][4];
#pragma unroll
  for (int i = 0; i < 4; ++i)
#pragma unroll
    for (int j = 0; j < 4; ++j) acc[i][j] = 0.f;

  float4 rx[4], rw[4];
#pragma unroll
  for (int i = 0; i < 4; ++i) {
    rx[i] = *reinterpret_cast<const float4*>(x + (size_t)(t0 + srow[i]) * ND + k0 + scol[i]);
    rw[i] = *reinterpret_cast<const float4*>(wg + (size_t)srow[i] * ND + k0 + scol[i]);
  }

  for (int tt = 0; tt < NT; ++tt) {
    __syncthreads();
#pragma unroll
    for (int i = 0; i < 4; ++i) {
      *reinterpret_cast<float4*>(&xs[srow[i]][scol[i]]) = rx[i];
      wk[scol[i] + 0][srow[i]] = rw[i].x;
      wk[scol[i] + 1][srow[i]] = rw[i].y;
      wk[scol[i] + 2][srow[i]] = rw[i].z;
      wk[scol[i] + 3][srow[i]] = rw[i].w;
    }
    __syncthreads();
    if (tt + 1 < NT) {
      const int kt = k0 + (tt + 1) * 64;
#pragma unroll
      for (int i = 0; i < 4; ++i) {
        rx[i] = *reinterpret_cast<const float4*>(x + (size_t)(t0 + srow[i]) * ND + kt + scol[i]);
        rw[i] = *reinterpret_cast<const float4*>(wg + (size_t)srow[i] * ND + kt + scol[i]);
      }
    }
#pragma unroll 2
    for (int k4 = 0; k4 < 64; k4 += 4) {
      float4 xa[4];
#pragma unroll
      for (int i = 0; i < 4; ++i)
        xa[i] = *reinterpret_cast<const float4*>(&xs[ty4 + i][k4]);
#define KKSTEP(F, O)                                                        \
      {                                                                     \
        float4 wb = *reinterpret_cast<const float4*>(&wk[k4 + O][tx4]);     \
        _Pragma("unroll")                                                   \
        for (int i = 0; i < 4; ++i) {                                       \
          const float a = xa[i].F;                                          \
          acc[i][0] = fmaf(a, wb.x, acc[i][0]);                             \
          acc[i][1] = fmaf(a, wb.y, acc[i][1]);                             \
          acc[i][2] = fmaf(a, wb.z, acc[i][2]);                             \
          acc[i][3] = fmaf(a, wb.w, acc[i][3]);                             \
        }                                                                   \
      }
      KKSTEP(x, 0) KKSTEP(y, 1) KKSTEP(z, 2) KKSTEP(w, 3)
#undef KKSTEP
    }
  }

  float* dst = lp + (size_t)kb * T_TOK * NE;
#pragma unroll
  for (int i = 0; i < 4; ++i) {
    float4 v = make_float4(acc[i][0], acc[i][1], acc[i][2], acc[i][3]);
    *reinterpret_cast<float4*>(dst + (size_t)(t0 + ty4 + i) * NE + tx4) = v;
  }
}

// ------------------------------------------------- epilogue: softmax/argmax
__global__ __launch_bounds__(256) void k_epi(
    const float* __restrict__ lp, const float* __restrict__ gum,
    int* __restrict__ idx1o, int* __restrict__ idx2o,
    float* __restrict__ g1o, float* __restrict__ g2o,
    float* __restrict__ meb) {
  __shared__ float mred[4][NE];
  const int tid = threadIdx.x;
  const int wave = tid >> 6;
  const int lane = tid & 63;
  const int t0 = blockIdx.x * 64;
  float meacc = 0.f;
  for (int tt = wave * 16; tt < wave * 16 + 16; ++tt) {
    const int t = t0 + tt;
    const float logit = lp[(size_t)t * NE + lane] +
                        lp[(size_t)(T_TOK + t) * NE + lane];
    float m = logit;
#pragma unroll
    for (int o = 32; o; o >>= 1) m = fmaxf(m, __shfl_xor(m, o));
    const float ex = expf(logit - m);
    float s = ex;
#pragma unroll
    for (int o = 32; o; o >>= 1) s += __shfl_xor(s, o);
    const float gate = ex / s;
    meacc += gate;
    float v1 = logit; int i1 = lane;
#pragma unroll
    for (int o = 32; o; o >>= 1) {
      float vv = __shfl_xor(v1, o); int jj = __shfl_xor(i1, o);
      if (vv > v1 || (vv == v1 && jj < i1)) { v1 = vv; i1 = jj; }
    }
    float v2 = (lane == i1) ? -__builtin_inff() : logit + gum[(size_t)t * NE + lane];
    int i2 = lane;
#pragma unroll
    for (int o = 32; o; o >>= 1) {
      float vv = __shfl_xor(v2, o); int jj = __shfl_xor(i2, o);
      if (vv > v2 || (vv == v2 && jj < i2)) { v2 = vv; i2 = jj; }
    }
    const float gv1 = __shfl(gate, i1);
    const float gv2 = __shfl(gate, i2);
    if (lane == 0) {
      idx1o[t] = i1; idx2o[t] = i2; g1o[t] = gv1; g2o[t] = gv2;
    }
  }
  mred[wave][lane] = meacc;
  __syncthreads();
  if (wave == 0) {
    float sm = mred[0][lane] + mred[1][lane] + mred[2][lane] + mred[3][lane];
    meb[(size_t)blockIdx.x * NE + lane] = sm;
  }
}

// ------------------------------------------------- per-expert token scan
__global__ __launch_bounds__(256) void k_scan(
    const int* __restrict__ idx1, const int* __restrict__ idx2,
    int* __restrict__ loc1, int* __restrict__ loc2, int* __restrict__ cnt1) {
  const int e = blockIdx.x;
  const int tid = threadIdx.x;
  const int base = tid * 32;
  int c1 = 0, c2 = 0;
  for (int i = 0; i < 32; ++i) {
    c1 += (idx1[base + i] == e);
    c2 += (idx2[base + i] == e);
  }
  const int lane = tid & 63, wave = tid >> 6;
  int s1 = c1, s2 = c2;
#pragma unroll
  for (int o = 1; o < 64; o <<= 1) {
    int t1 = __shfl_up(s1, o), t2 = __shfl_up(s2, o);
    if (lane >= o) { s1 += t1; s2 += t2; }
  }
  __shared__ int wt1[4], wt2[4];
  if (lane == 63) { wt1[wave] = s1; wt2[wave] = s2; }
  __syncthreads();
  int off1 = 0, off2 = 0, tot1 = 0;
#pragma unroll
  for (int w = 0; w < 4; ++w) {
    tot1 += wt1[w];
    if (w < wave) { off1 += wt1[w]; off2 += wt2[w]; }
  }
  int p1 = off1 + s1 - c1;
  int p2 = off2 + s2 - c2 + tot1;
  for (int i = 0; i < 32; ++i) {
    if (idx1[base + i] == e) loc1[base + i] = p1++;
    if (idx2[base + i] == e) loc2[base + i] = p2++;
  }
  if (tid == 0) cnt1[e] = tot1;
}

// ------------------------------------- scatter combine/dispatch + l_aux
__global__ __launch_bounds__(256) void k_scat(
    const int* __restrict__ idx1, const int* __restrict__ idx2,
    const float* __restrict__ g1, const float* __restrict__ g2,
    const int* __restrict__ loc1, const int* __restrict__ loc2,
    const float* __restrict__ meb, const int* __restrict__ cnt1,
    float* __restrict__ out) {
  if (blockIdx.x == T_TOK / 256) {
    const int lane = threadIdx.x;
    if (lane >= 64) return;
    float ms = 0.f;
    for (int b = 0; b < MEB_B; ++b) ms += meb[(size_t)b * NE + lane];
    const float me = ms / (float)T_TOK;
    const float ce = (float)cnt1[lane] / (float)T_TOK;
    float v = me * ce;
#pragma unroll
    for (int o = 32; o; o >>= 1) v += __shfl_xor(v, o);
    if (lane == 0) out[0] = v * (float)NE;
    return;
  }
  const int t = blockIdx.x * 256 + threadIdx.x;
  const int l1 = loc1[t], l2 = loc2[t];
  const bool k1 = l1 < CAP, k2 = l2 < CAP;
  const float a = k1 ? g1[t] : 0.f;
  const float b = k2 ? g2[t] : 0.f;
  const float denom = fmaxf(a + b, 1.1920929e-07f);
  float* cw = out + 1;
  float* dm = out + 1 + (size_t)T_TOK * NE * CAP;
  if (k1) {
    size_t o = ((size_t)t * NE + idx1[t]) * CAP + l1;
    cw[o] = a / denom; dm[o] = 1.0f;
  }
  if (k2) {
    size_t o = ((size_t)t * NE + idx2[t]) * CAP + l2;
    cw[o] = b / denom; dm[o] = 1.0f;
  }
}

// ---------------------------------------------------------------- launcher
extern "C" void kernel_launch(void* const* d_in, const int* in_sizes, int n_in,
                              void* d_out, int out_size, void* d_ws, size_t ws_size,
                              hipStream_t stream) {
  const float* x   = (const float*)d_in[0];   // [8192, 2048]
  const float* wg  = (const float*)d_in[1];   // [64, 2048]
  const float* gum = (const float*)d_in[2];   // [8192, 64]
  float* out = (float*)d_out;

  // workspace layout (~4.5 MB)
  char* ws = (char*)d_ws;
  float* lp   = (float*)(ws + 0);             // [2][8192][64] = 4 MB
  int*   idx1 = (int*)(ws + 4194304);
  int*   idx2 = (int*)(ws + 4227072);
  float* g1   = (float*)(ws + 4259840);
  float* g2   = (float*)(ws + 4292608);
  int*   loc1 = (int*)(ws + 4325376);
  int*   loc2 = (int*)(ws + 4358144);
  int*   cnt1 = (int*)(ws + 4390912);
  float* meb  = (float*)(ws + 4391168);       // [128][64]

  const long n  = (long)out_size;             // 268,435,457 floats
  const long n4 = n >> 2;

  // serial chain; ONLY change vs R9: fill grid 2048 -> 256 blocks
  k_zero<<<dim3(ZB), dim3(256), 0, stream>>>((float4*)out, n4, out, n);
  kG<<<dim3(GB2), dim3(256), 0, stream>>>(x, wg, lp);
  k_epi<<<dim3(T_TOK / 64), dim3(256), 0, stream>>>(lp, gum, idx1, idx2, g1, g2, meb);
  k_scan<<<dim3(NE), dim3(256), 0, stream>>>(idx1, idx2, loc1, loc2, cnt1);
  k_scat<<<dim3(T_TOK / 256 + 1), dim3(256), 0, stream>>>(
      idx1, idx2, g1, g2, loc1, loc2, meb, cnt1, out);
}